// Round 5
// baseline (1489.537 us; speedup 1.0000x reference)
//
#include <hip/hip_runtime.h>
#include <stdint.h>

#define T_SEQ 256
#define NB    8
#define EMB   512
#define HID   1024
#define NOUT  32000
#define RING  16
#define SEN   0x40004000u
#define NTILE_M 16
#define NTILE_N 250
#define NTICKETS (NTILE_M * NTILE_N)
#define RBLK  64

typedef float    f32x4  __attribute__((ext_vector_type(4)));
typedef unsigned int u32x4 __attribute__((ext_vector_type(4)));
typedef __bf16   bf16x8 __attribute__((ext_vector_type(8)));

#define AS1 __attribute__((address_space(1)))
#define AS3 __attribute__((address_space(3)))

__device__ __forceinline__ uint32_t f2bf(float f) {
    uint32_t u = __builtin_bit_cast(uint32_t, f);
    u += 0x7FFFu + ((u >> 16) & 1u);   // RNE
    return (u >> 16);
}

__device__ __forceinline__ bf16x8 mk_hi(u32x4 a, u32x4 b) {
    u32x4 r;
    r.x = __builtin_amdgcn_perm(a.y, a.x, 0x07060302u);
    r.y = __builtin_amdgcn_perm(a.w, a.z, 0x07060302u);
    r.z = __builtin_amdgcn_perm(b.y, b.x, 0x07060302u);
    r.w = __builtin_amdgcn_perm(b.w, b.z, 0x07060302u);
    return __builtin_bit_cast(bf16x8, r);
}
__device__ __forceinline__ bf16x8 mk_lo(u32x4 a, u32x4 b) {
    u32x4 r;
    r.x = __builtin_amdgcn_perm(a.y, a.x, 0x05040100u);
    r.y = __builtin_amdgcn_perm(a.w, a.z, 0x05040100u);
    r.z = __builtin_amdgcn_perm(b.y, b.x, 0x05040100u);
    r.w = __builtin_amdgcn_perm(b.w, b.z, 0x05040100u);
    return __builtin_bit_cast(bf16x8, r);
}

// ---------------- sentinel fill of the packed-h ring ----------------
__global__ void k_fill(unsigned int* __restrict__ p) {  // RING*8*1024 u32 = 512 KB
    int i = blockIdx.x * blockDim.x + threadIdx.x;      // 128 x 256 x 4
    u32x4 v = { SEN, SEN, SEN, SEN };
    unsigned int* addr = p + (size_t)i * 4;
    asm volatile("global_store_dwordx4 %0, %1, off sc0 sc1"
                 :: "v"(addr), "v"(v) : "memory");
}

// ---------------- embed gather + xproj = emb @ W_ih^T + b_ih (fp32) ----------------
__global__ __launch_bounds__(256) void k_xproj(
        const int* __restrict__ inputs, const float* __restrict__ embed,
        const float* __restrict__ W_ih, const float* __restrict__ b_ih,
        float* __restrict__ xproj) {
    __shared__ float As[64][33];
    __shared__ float Bs[64][33];
    __shared__ int   idx_s[64];
    const int tid = threadIdx.x;
    const int bm = blockIdx.y, bn = blockIdx.x;
    if (tid < 64) {
        int m = bm * 64 + tid;
        idx_s[tid] = inputs[(m & 7) * T_SEQ + (m >> 3)];
    }
    __syncthreads();
    const int ty = tid >> 4, tx = tid & 15;
    const int lr = tid >> 2, lc = (tid & 3) * 8;
    float acc[4][4] = {};
    for (int kk = 0; kk < EMB; kk += 32) {
        __syncthreads();
        const float* arow = embed + (size_t)idx_s[lr] * EMB + kk + lc;
        f32x4 a0 = *(const f32x4*)arow;
        f32x4 a1 = *(const f32x4*)(arow + 4);
        const float* brow = W_ih + (size_t)(bn * 64 + lr) * EMB + kk + lc;
        f32x4 b0 = *(const f32x4*)brow;
        f32x4 b1 = *(const f32x4*)(brow + 4);
#pragma unroll
        for (int u = 0; u < 4; ++u) {
            As[lr][lc + u] = a0[u]; As[lr][lc + 4 + u] = a1[u];
            Bs[lr][lc + u] = b0[u]; Bs[lr][lc + 4 + u] = b1[u];
        }
        __syncthreads();
#pragma unroll
        for (int k = 0; k < 32; ++k) {
            float av[4], bv[4];
#pragma unroll
            for (int i = 0; i < 4; ++i) av[i] = As[ty * 4 + i][k];
#pragma unroll
            for (int j = 0; j < 4; ++j) bv[j] = Bs[tx * 4 + j][k];
#pragma unroll
            for (int i = 0; i < 4; ++i)
#pragma unroll
                for (int j = 0; j < 4; ++j) acc[i][j] += av[i] * bv[j];
        }
    }
#pragma unroll
    for (int i = 0; i < 4; ++i) {
        int m = bm * 64 + ty * 4 + i;
#pragma unroll
        for (int j = 0; j < 4; ++j) {
            int n = bn * 64 + tx * 4 + j;
            xproj[(size_t)m * HID + n] = acc[i][j] + b_ih[n];
        }
    }
}

// ---------------- mega kernel: blocks 0-63 = rnn agents, all blocks = fc workers ----------------
__global__ __launch_bounds__(256, 1) void k_mega(
        const float* __restrict__ W_hh, const float* __restrict__ b_hh,
        const float* __restrict__ xproj,
        unsigned int* __restrict__ hpk /* [RING][8][1024] u32 */,
        unsigned short* __restrict__ hs /* [2048][1024] bf16 */,
        const float* __restrict__ W_fc, const float* __restrict__ b_fc,
        float* __restrict__ out,
        unsigned int* __restrict__ prog /* [64] */,
        unsigned int* __restrict__ ticket /* [1] */) {
    __shared__ __align__(16) char smem_raw[24592];
    const int tid = threadIdx.x;
    const int w   = tid >> 6;
    const int ln  = tid & 63;
    const int blk = blockIdx.x;

    if (blk < RBLK) {
        // ================= RNN role (structure identical to R4) =================
        float (*part)[4][64][4] = (float (*)[4][64][4])smem_raw;   // 8 KB dbuf
        const float* wrow = W_hh + (size_t)(blk * 16 + (ln & 15)) * HID;
        bf16x8 whi[8], wlo[8];
#pragma unroll
        for (int cc = 0; cc < 8; ++cc) {
            int k0 = w * 256 + cc * 32 + (ln >> 4) * 8;
            f32x4 wa = *(const f32x4*)(wrow + k0);
            f32x4 wb = *(const f32x4*)(wrow + k0 + 4);
            float wv[8] = { wa.x, wa.y, wa.z, wa.w, wb.x, wb.y, wb.z, wb.w };
            uint32_t hu[8], lu[8];
#pragma unroll
            for (int j = 0; j < 8; ++j) {
                hu[j] = f2bf(wv[j]);
                float hif = __builtin_bit_cast(float, hu[j] << 16);
                lu[j] = f2bf(wv[j] - hif);
            }
            u32x4 ph = { hu[0] | (hu[1] << 16), hu[2] | (hu[3] << 16),
                         hu[4] | (hu[5] << 16), hu[6] | (hu[7] << 16) };
            u32x4 pl = { lu[0] | (lu[1] << 16), lu[2] | (lu[3] << 16),
                         lu[4] | (lu[5] << 16), lu[6] | (lu[7] << 16) };
            whi[cc] = __builtin_bit_cast(bf16x8, ph);
            wlo[cc] = __builtin_bit_cast(bf16x8, pl);
        }

        const float bhh = b_hh[blk * 16 + (ln & 15)];
        const int frag_k = w * 256 + (ln >> 4) * 8;

        for (int t = 0; t < T_SEQ; ++t) {
            float xp[4];
            if (w == 0) {
                int colp = blk * 16 + (ln & 15);
                int bb = (ln >> 4) * 4;
#pragma unroll
                for (int r = 0; r < 4; ++r) {
                    int b = (bb + r) & 7;
                    xp[r] = xproj[(size_t)(t * NB + b) * HID + colp];
                }
            }

            f32x4 acc0 = {0.f, 0.f, 0.f, 0.f}, acc1 = {0.f, 0.f, 0.f, 0.f};
            if (t > 0) {
                const unsigned int* hp = hpk + (size_t)((t - 1) & (RING - 1)) * 8192
                                             + (ln & 7) * 1024 + frag_k;
                u32x4 q0, q1, q2, q3, q4, q5, q6, q7, q8, q9, q10, q11, q12, q13, q14, q15;
                uint32_t bad;
                do {
                    asm volatile(
                        "global_load_dwordx4 %0, %16, off sc0 sc1\n\t"
                        "global_load_dwordx4 %1, %16, off offset:16 sc0 sc1\n\t"
                        "global_load_dwordx4 %2, %16, off offset:128 sc0 sc1\n\t"
                        "global_load_dwordx4 %3, %16, off offset:144 sc0 sc1\n\t"
                        "global_load_dwordx4 %4, %16, off offset:256 sc0 sc1\n\t"
                        "global_load_dwordx4 %5, %16, off offset:272 sc0 sc1\n\t"
                        "global_load_dwordx4 %6, %16, off offset:384 sc0 sc1\n\t"
                        "global_load_dwordx4 %7, %16, off offset:400 sc0 sc1\n\t"
                        "global_load_dwordx4 %8, %16, off offset:512 sc0 sc1\n\t"
                        "global_load_dwordx4 %9, %16, off offset:528 sc0 sc1\n\t"
                        "global_load_dwordx4 %10, %16, off offset:640 sc0 sc1\n\t"
                        "global_load_dwordx4 %11, %16, off offset:656 sc0 sc1\n\t"
                        "global_load_dwordx4 %12, %16, off offset:768 sc0 sc1\n\t"
                        "global_load_dwordx4 %13, %16, off offset:784 sc0 sc1\n\t"
                        "global_load_dwordx4 %14, %16, off offset:896 sc0 sc1\n\t"
                        "global_load_dwordx4 %15, %16, off offset:912 sc0 sc1\n\t"
                        "s_waitcnt vmcnt(0)"
                        : "=&v"(q0), "=&v"(q1), "=&v"(q2), "=&v"(q3),
                          "=&v"(q4), "=&v"(q5), "=&v"(q6), "=&v"(q7),
                          "=&v"(q8), "=&v"(q9), "=&v"(q10), "=&v"(q11),
                          "=&v"(q12), "=&v"(q13), "=&v"(q14), "=&v"(q15)
                        : "v"(hp)
                        : "memory");
                    bad = 0;
#define CKQ(q) bad |= (uint32_t)((q.x == SEN) | (q.y == SEN) | (q.z == SEN) | (q.w == SEN))
                    CKQ(q0); CKQ(q1); CKQ(q2); CKQ(q3); CKQ(q4); CKQ(q5); CKQ(q6); CKQ(q7);
                    CKQ(q8); CKQ(q9); CKQ(q10); CKQ(q11); CKQ(q12); CKQ(q13); CKQ(q14); CKQ(q15);
#undef CKQ
                } while (bad);

#define DO_CHUNK(qa, qb, WH, WL, ACC) do {                                          \
                bf16x8 ah = mk_hi(qa, qb);                                          \
                bf16x8 al = mk_lo(qa, qb);                                          \
                ACC = __builtin_amdgcn_mfma_f32_16x16x32_bf16(ah, WH, ACC, 0, 0, 0);\
                ACC = __builtin_amdgcn_mfma_f32_16x16x32_bf16(al, WH, ACC, 0, 0, 0);\
                ACC = __builtin_amdgcn_mfma_f32_16x16x32_bf16(ah, WL, ACC, 0, 0, 0);\
            } while (0)
                DO_CHUNK(q0,  q1,  whi[0], wlo[0], acc0);
                DO_CHUNK(q2,  q3,  whi[1], wlo[1], acc1);
                DO_CHUNK(q4,  q5,  whi[2], wlo[2], acc0);
                DO_CHUNK(q6,  q7,  whi[3], wlo[3], acc1);
                DO_CHUNK(q8,  q9,  whi[4], wlo[4], acc0);
                DO_CHUNK(q10, q11, whi[5], wlo[5], acc1);
                DO_CHUNK(q12, q13, whi[6], wlo[6], acc0);
                DO_CHUNK(q14, q15, whi[7], wlo[7], acc1);
#undef DO_CHUNK
            }
            f32x4 asum = acc0 + acc1;
            *(f32x4*)&part[t & 1][w][ln][0] = asum;
            __syncthreads();

            if (w == 0) {
                f32x4 p0 = *(const f32x4*)&part[t & 1][0][ln][0];
                f32x4 p1 = *(const f32x4*)&part[t & 1][1][ln][0];
                f32x4 p2 = *(const f32x4*)&part[t & 1][2][ln][0];
                f32x4 p3 = *(const f32x4*)&part[t & 1][3][ln][0];
                f32x4 csum = (p0 + p1) + (p2 + p3);
                if (ln < 32) {
                    int colp = blk * 16 + (ln & 15);
                    int bb = (ln >> 4) * 4;
                    unsigned int* slot_w = hpk + (size_t)(t & (RING - 1)) * 8192;
                    unsigned int* slot_s = hpk + (size_t)((t + RING - 3) & (RING - 1)) * 8192;
                    uint32_t pk[4], hb[4];
#pragma unroll
                    for (int r = 0; r < 4; ++r) {
                        float x = xp[r] + csum[r] + bhh;
                        float h = tanhf(x);
                        uint32_t hi = f2bf(h);
                        float hif = __builtin_bit_cast(float, hi << 16);
                        uint32_t lo = f2bf(h - hif);
                        pk[r] = (hi << 16) | lo;
                        hb[r] = hi;
                    }
                    // 1) publish h-ring FIRST (consumers gate on this)
#pragma unroll
                    for (int r = 0; r < 4; ++r) {
                        unsigned int* ha = slot_w + (bb + r) * 1024 + colp;
                        asm volatile("global_store_dword %0, %1, off sc0 sc1"
                                     :: "v"(ha), "v"(pk[r]) : "memory");
                    }
                    // 2) sentinel refill of slot t+13
#pragma unroll
                    for (int r = 0; r < 4; ++r) {
                        unsigned int* sa = slot_s + (bb + r) * 1024 + colp;
                        unsigned int sv = SEN;
                        asm volatile("global_store_dword %0, %1, off sc0 sc1"
                                     :: "v"(sa), "v"(sv) : "memory");
                    }
                    // 3) hs archive (write-through so fc workers can read it)
#pragma unroll
                    for (int r = 0; r < 4; ++r) {
                        unsigned short* aa = hs + (size_t)(t * NB + bb + r) * HID + colp;
                        asm volatile("global_store_short %0, %1, off sc0 sc1"
                                     :: "v"(aa), "v"(hb[r]) : "memory");
                    }
                }
                // release: drain all stores, then publish progress
                asm volatile("s_waitcnt vmcnt(0)" ::: "memory");
                if (ln == 0) {
                    unsigned int tv = (unsigned int)(t + 1);
                    unsigned int* pp = prog + blk;
                    asm volatile("global_store_dword %0, %1, off sc0 sc1"
                                 :: "v"(pp), "v"(tv) : "memory");
                }
            }
        }
        __syncthreads();   // done with `part`; smem becomes fc staging below
    }

    // ================= FC worker role (all blocks; rnn blocks join after t loop) =================
    unsigned short* As  = (unsigned short*)smem_raw;          // 8 KB  [128][32] bf16
    float*          Bsf = (float*)(smem_raw + 8192);          // 16 KB [128][32] f32
    int* ticket_s = (int*)(smem_raw + 24576);
    const int wm = (w >> 1) * 64, wn = (w & 1) * 64;
    const int fr = ln & 15;
    const int kq = (ln >> 4) * 8;

    for (;;) {
        __syncthreads();
        if (tid == 0) *ticket_s = (int)atomicAdd(ticket, 1u);
        __syncthreads();
        int id = *ticket_s;
        if (id >= NTICKETS) break;
        int bm = id / NTILE_N;
        int bn = id - bm * NTILE_N;

        // gate: all 64 rnn blocks past step (bm+1)*16
        if (w == 0) {
            unsigned int target = (unsigned int)(bm + 1) * 16u;
            const unsigned int* pp = prog + ln;
            for (;;) {
                unsigned int v;
                asm volatile("global_load_dword %0, %1, off sc0 sc1\n\t"
                             "s_waitcnt vmcnt(0)"
                             : "=v"(v) : "v"(pp) : "memory");
                if (__all(v >= target)) break;
                __builtin_amdgcn_s_sleep(8);
            }
        }
        __syncthreads();

        const unsigned short* Ag = hs + (size_t)(bm * 128 + (tid >> 2)) * 1024 + (tid & 3) * 8;
        const float* BgBase = W_fc + (size_t)(bn * 128) * 1024;
        f32x4 acc[4][4] = {};

        for (int kk = 0; kk < 1024; kk += 32) {
            __syncthreads();
            __builtin_amdgcn_global_load_lds((const AS1 void*)(Ag + kk),
                                             (AS3 void*)(As + w * 512), 16, 0, 0);
            __builtin_amdgcn_global_load_lds((const AS1 void*)(Ag + 64 * 1024 + kk),
                                             (AS3 void*)(As + 2048 + w * 512), 16, 0, 0);
#pragma unroll
            for (int p = 0; p < 4; ++p) {
                const float* bsrc = BgBase + (size_t)(p * 32 + w * 8 + (ln >> 3)) * 1024
                                  + kk + (ln & 7) * 4;
                __builtin_amdgcn_global_load_lds((const AS1 void*)bsrc,
                                                 (AS3 void*)((char*)Bsf + p * 4096 + w * 1024),
                                                 16, 0, 0);
            }
            __syncthreads();
            bf16x8 af[4], bfj[4];
#pragma unroll
            for (int i = 0; i < 4; ++i)
                af[i] = *(const bf16x8*)&As[(wm + i * 16 + fr) * 32 + kq];
#pragma unroll
            for (int j = 0; j < 4; ++j) {
                const float* bp = &Bsf[(wn + j * 16 + fr) * 32 + kq];
                f32x4 b0 = *(const f32x4*)bp;
                f32x4 b1 = *(const f32x4*)(bp + 4);
                u32x4 bw;
                asm("v_cvt_pk_bf16_f32 %0, %1, %2" : "=v"(bw.x) : "v"(b0.x), "v"(b0.y));
                asm("v_cvt_pk_bf16_f32 %0, %1, %2" : "=v"(bw.y) : "v"(b0.z), "v"(b0.w));
                asm("v_cvt_pk_bf16_f32 %0, %1, %2" : "=v"(bw.z) : "v"(b1.x), "v"(b1.y));
                asm("v_cvt_pk_bf16_f32 %0, %1, %2" : "=v"(bw.w) : "v"(b1.z), "v"(b1.w));
                bfj[j] = __builtin_bit_cast(bf16x8, bw);
            }
#pragma unroll
            for (int i = 0; i < 4; ++i)
#pragma unroll
                for (int j = 0; j < 4; ++j)
                    acc[i][j] = __builtin_amdgcn_mfma_f32_16x16x32_bf16(af[i], bfj[j], acc[i][j], 0, 0, 0);
        }

        const int fq = ln >> 4;
#pragma unroll
        for (int i = 0; i < 4; ++i) {
#pragma unroll
            for (int j = 0; j < 4; ++j) {
                int n = bn * 128 + wn + j * 16 + fr;
                float bv = b_fc[n];
#pragma unroll
                for (int r = 0; r < 4; ++r) {
                    int m = bm * 128 + wm + i * 16 + fq * 4 + r;
                    int t = m >> 3, b = m & 7;
                    out[(size_t)b * T_SEQ * NOUT + (size_t)t * NOUT + n] = acc[i][j][r] + bv;
                }
            }
        }
    }
}

extern "C" void kernel_launch(void* const* d_in, const int* in_sizes, int n_in,
                              void* d_out, int out_size, void* d_ws, size_t ws_size,
                              hipStream_t stream) {
    const int*   inputs = (const int*)d_in[0];
    const float* embed  = (const float*)d_in[1];
    const float* W_ih   = (const float*)d_in[2];
    const float* W_hh   = (const float*)d_in[3];
    const float* b_ih   = (const float*)d_in[4];
    const float* b_hh   = (const float*)d_in[5];
    const float* W_fc   = (const float*)d_in[6];
    const float* b_fc   = (const float*)d_in[7];
    float* out = (float*)d_out;

    char* ws = (char*)d_ws;
    unsigned int*   prog   = (unsigned int*)(ws);                    // 256 B
    unsigned int*   ticket = (unsigned int*)(ws + 256);              // 4 B (pad to 512)
    unsigned int*   hpk    = (unsigned int*)(ws + 512);              // 512 KB
    float*          xproj  = (float*)(ws + 512 + 524288);            // 8 MB
    unsigned short* hs     = (unsigned short*)(ws + 512 + 524288 + 8388608); // 4 MB

    hipMemsetAsync(ws, 0, 512, stream);
    k_fill<<<128, 256, 0, stream>>>(hpk);
    k_xproj<<<dim3(16, 32), 256, 0, stream>>>(inputs, embed, W_ih, b_ih, xproj);
    k_mega<<<256, 256, 0, stream>>>(W_hh, b_hh, xproj, hpk, hs,
                                    W_fc, b_fc, out, prog, ticket);
}

// Round 6
// 1397.888 us; speedup vs baseline: 1.0656x; 1.0656x over previous
//
#include <hip/hip_runtime.h>
#include <stdint.h>

#define T_SEQ 256
#define NB    8
#define EMB   512
#define HID   1024
#define NOUT  32000
#define RING  16
#define SEN   0x40004000u

typedef float    f32x4  __attribute__((ext_vector_type(4)));
typedef unsigned int u32x4 __attribute__((ext_vector_type(4)));
typedef __bf16   bf16x8 __attribute__((ext_vector_type(8)));

#define AS1 __attribute__((address_space(1)))
#define AS3 __attribute__((address_space(3)))

__device__ __forceinline__ uint32_t f2bf(float f) {
    uint32_t u = __builtin_bit_cast(uint32_t, f);
    u += 0x7FFFu + ((u >> 16) & 1u);   // RNE
    return (u >> 16);
}

__device__ __forceinline__ bf16x8 mk_hi(u32x4 a, u32x4 b) {
    u32x4 r;
    r.x = __builtin_amdgcn_perm(a.y, a.x, 0x07060302u);
    r.y = __builtin_amdgcn_perm(a.w, a.z, 0x07060302u);
    r.z = __builtin_amdgcn_perm(b.y, b.x, 0x07060302u);
    r.w = __builtin_amdgcn_perm(b.w, b.z, 0x07060302u);
    return __builtin_bit_cast(bf16x8, r);
}
__device__ __forceinline__ bf16x8 mk_lo(u32x4 a, u32x4 b) {
    u32x4 r;
    r.x = __builtin_amdgcn_perm(a.y, a.x, 0x05040100u);
    r.y = __builtin_amdgcn_perm(a.w, a.z, 0x05040100u);
    r.z = __builtin_amdgcn_perm(b.y, b.x, 0x05040100u);
    r.w = __builtin_amdgcn_perm(b.w, b.z, 0x05040100u);
    return __builtin_bit_cast(bf16x8, r);
}

// ---------------- sentinel fill of the packed-h ring ----------------
// atomic exchange: executes at the coherent point -> lines start MALL-resident
__global__ void k_fill(unsigned int* __restrict__ p) {  // RING*8*1024 u32 = 512 KB
    int i = blockIdx.x * blockDim.x + threadIdx.x;      // 128 x 256 x 4
    unsigned int* a = p + (size_t)i * 4;
#pragma unroll
    for (int j = 0; j < 4; ++j)
        (void)__hip_atomic_exchange(a + j, SEN, __ATOMIC_RELAXED, __HIP_MEMORY_SCOPE_AGENT);
}

// ---------------- W_fc fp32 -> bf16 ----------------
__global__ void k_convert_wfc(const float* __restrict__ src, unsigned short* __restrict__ dst) {
    int i = blockIdx.x * blockDim.x + threadIdx.x;
    const f32x4* s4 = (const f32x4*)src;
    int n4 = NOUT * HID / 4;
    int stride = gridDim.x * blockDim.x;
    for (int idx = i; idx < n4; idx += stride) {
        f32x4 v = s4[idx];
        uint2 o;
        o.x = f2bf(v.x) | (f2bf(v.y) << 16);
        o.y = f2bf(v.z) | (f2bf(v.w) << 16);
        ((uint2*)dst)[idx] = o;
    }
}

// ---------------- embed gather + xproj = emb @ W_ih^T + b_ih (fp32) ----------------
__global__ __launch_bounds__(256) void k_xproj(
        const int* __restrict__ inputs, const float* __restrict__ embed,
        const float* __restrict__ W_ih, const float* __restrict__ b_ih,
        float* __restrict__ xproj) {
    __shared__ float As[64][33];
    __shared__ float Bs[64][33];
    __shared__ int   idx_s[64];
    const int tid = threadIdx.x;
    const int bm = blockIdx.y, bn = blockIdx.x;
    if (tid < 64) {
        int m = bm * 64 + tid;
        idx_s[tid] = inputs[(m & 7) * T_SEQ + (m >> 3)];
    }
    __syncthreads();
    const int ty = tid >> 4, tx = tid & 15;
    const int lr = tid >> 2, lc = (tid & 3) * 8;
    float acc[4][4] = {};
    for (int kk = 0; kk < EMB; kk += 32) {
        __syncthreads();
        const float* arow = embed + (size_t)idx_s[lr] * EMB + kk + lc;
        f32x4 a0 = *(const f32x4*)arow;
        f32x4 a1 = *(const f32x4*)(arow + 4);
        const float* brow = W_ih + (size_t)(bn * 64 + lr) * EMB + kk + lc;
        f32x4 b0 = *(const f32x4*)brow;
        f32x4 b1 = *(const f32x4*)(brow + 4);
#pragma unroll
        for (int u = 0; u < 4; ++u) {
            As[lr][lc + u] = a0[u]; As[lr][lc + 4 + u] = a1[u];
            Bs[lr][lc + u] = b0[u]; Bs[lr][lc + 4 + u] = b1[u];
        }
        __syncthreads();
#pragma unroll
        for (int k = 0; k < 32; ++k) {
            float av[4], bv[4];
#pragma unroll
            for (int i = 0; i < 4; ++i) av[i] = As[ty * 4 + i][k];
#pragma unroll
            for (int j = 0; j < 4; ++j) bv[j] = Bs[tx * 4 + j][k];
#pragma unroll
            for (int i = 0; i < 4; ++i)
#pragma unroll
                for (int j = 0; j < 4; ++j) acc[i][j] += av[i] * bv[j];
        }
    }
#pragma unroll
    for (int i = 0; i < 4; ++i) {
        int m = bm * 64 + ty * 4 + i;
#pragma unroll
        for (int j = 0; j < 4; ++j) {
            int n = bn * 64 + tx * 4 + j;
            xproj[(size_t)m * HID + n] = acc[i][j] + b_ih[n];
        }
    }
}

// ---------------- persistent recurrence: 64 blocks x 256 threads, MFMA ----------------
// h published as packed u32 via device-scope atomic_exchange (lands at the
// coherent point, stays MALL-resident — no HBM write-through/invalidate).
// Sentinel poll (sc0 sc1 loads, MALL-hit) = fragment load. Split-bf16 3-MFMA.
#define RBLK 64
__global__ __launch_bounds__(256, 1) void k_rnn(
        const float* __restrict__ W_hh, const float* __restrict__ b_hh,
        const float* __restrict__ xproj,
        unsigned int* __restrict__ hpk /* [RING][8][1024] u32 */,
        unsigned short* __restrict__ hs /* [2048][1024] bf16 */) {
    __shared__ __align__(16) float part[2][4][64][4];   // 8 KB, dbuf by t&1
    const int tid = threadIdx.x;
    const int w   = tid >> 6;
    const int ln  = tid & 63;
    const int blk = blockIdx.x;

    const float* wrow = W_hh + (size_t)(blk * 16 + (ln & 15)) * HID;
    bf16x8 whi[8], wlo[8];
#pragma unroll
    for (int cc = 0; cc < 8; ++cc) {
        int k0 = w * 256 + cc * 32 + (ln >> 4) * 8;
        f32x4 wa = *(const f32x4*)(wrow + k0);
        f32x4 wb = *(const f32x4*)(wrow + k0 + 4);
        float wv[8] = { wa.x, wa.y, wa.z, wa.w, wb.x, wb.y, wb.z, wb.w };
        uint32_t hu[8], lu[8];
#pragma unroll
        for (int j = 0; j < 8; ++j) {
            hu[j] = f2bf(wv[j]);
            float hif = __builtin_bit_cast(float, hu[j] << 16);
            lu[j] = f2bf(wv[j] - hif);
        }
        u32x4 ph = { hu[0] | (hu[1] << 16), hu[2] | (hu[3] << 16),
                     hu[4] | (hu[5] << 16), hu[6] | (hu[7] << 16) };
        u32x4 pl = { lu[0] | (lu[1] << 16), lu[2] | (lu[3] << 16),
                     lu[4] | (lu[5] << 16), lu[6] | (lu[7] << 16) };
        whi[cc] = __builtin_bit_cast(bf16x8, ph);
        wlo[cc] = __builtin_bit_cast(bf16x8, pl);
    }

    const float bhh = b_hh[blk * 16 + (ln & 15)];
    const int frag_k = w * 256 + (ln >> 4) * 8;

    for (int t = 0; t < T_SEQ; ++t) {
        float xp[4];
        if (w == 0) {
            int colp = blk * 16 + (ln & 15);
            int bb = (ln >> 4) * 4;
#pragma unroll
            for (int r = 0; r < 4; ++r) {
                int b = (bb + r) & 7;
                xp[r] = xproj[(size_t)(t * NB + b) * HID + colp];
            }
        }

        f32x4 acc0 = {0.f, 0.f, 0.f, 0.f}, acc1 = {0.f, 0.f, 0.f, 0.f};
        if (t > 0) {
            const unsigned int* hp = hpk + (size_t)((t - 1) & (RING - 1)) * 8192
                                         + (ln & 7) * 1024 + frag_k;
            u32x4 q0, q1, q2, q3, q4, q5, q6, q7, q8, q9, q10, q11, q12, q13, q14, q15;
            uint32_t bad;
            do {
                asm volatile(
                    "global_load_dwordx4 %0, %16, off sc0 sc1\n\t"
                    "global_load_dwordx4 %1, %16, off offset:16 sc0 sc1\n\t"
                    "global_load_dwordx4 %2, %16, off offset:128 sc0 sc1\n\t"
                    "global_load_dwordx4 %3, %16, off offset:144 sc0 sc1\n\t"
                    "global_load_dwordx4 %4, %16, off offset:256 sc0 sc1\n\t"
                    "global_load_dwordx4 %5, %16, off offset:272 sc0 sc1\n\t"
                    "global_load_dwordx4 %6, %16, off offset:384 sc0 sc1\n\t"
                    "global_load_dwordx4 %7, %16, off offset:400 sc0 sc1\n\t"
                    "global_load_dwordx4 %8, %16, off offset:512 sc0 sc1\n\t"
                    "global_load_dwordx4 %9, %16, off offset:528 sc0 sc1\n\t"
                    "global_load_dwordx4 %10, %16, off offset:640 sc0 sc1\n\t"
                    "global_load_dwordx4 %11, %16, off offset:656 sc0 sc1\n\t"
                    "global_load_dwordx4 %12, %16, off offset:768 sc0 sc1\n\t"
                    "global_load_dwordx4 %13, %16, off offset:784 sc0 sc1\n\t"
                    "global_load_dwordx4 %14, %16, off offset:896 sc0 sc1\n\t"
                    "global_load_dwordx4 %15, %16, off offset:912 sc0 sc1\n\t"
                    "s_waitcnt vmcnt(0)"
                    : "=&v"(q0), "=&v"(q1), "=&v"(q2), "=&v"(q3),
                      "=&v"(q4), "=&v"(q5), "=&v"(q6), "=&v"(q7),
                      "=&v"(q8), "=&v"(q9), "=&v"(q10), "=&v"(q11),
                      "=&v"(q12), "=&v"(q13), "=&v"(q14), "=&v"(q15)
                    : "v"(hp)
                    : "memory");
                bad = 0;
#define CKQ(q) bad |= (uint32_t)((q.x == SEN) | (q.y == SEN) | (q.z == SEN) | (q.w == SEN))
                CKQ(q0); CKQ(q1); CKQ(q2); CKQ(q3); CKQ(q4); CKQ(q5); CKQ(q6); CKQ(q7);
                CKQ(q8); CKQ(q9); CKQ(q10); CKQ(q11); CKQ(q12); CKQ(q13); CKQ(q14); CKQ(q15);
#undef CKQ
            } while (bad);

#define DO_CHUNK(qa, qb, WH, WL, ACC) do {                                          \
            bf16x8 ah = mk_hi(qa, qb);                                              \
            bf16x8 al = mk_lo(qa, qb);                                              \
            ACC = __builtin_amdgcn_mfma_f32_16x16x32_bf16(ah, WH, ACC, 0, 0, 0);    \
            ACC = __builtin_amdgcn_mfma_f32_16x16x32_bf16(al, WH, ACC, 0, 0, 0);    \
            ACC = __builtin_amdgcn_mfma_f32_16x16x32_bf16(ah, WL, ACC, 0, 0, 0);    \
        } while (0)
            DO_CHUNK(q0,  q1,  whi[0], wlo[0], acc0);
            DO_CHUNK(q2,  q3,  whi[1], wlo[1], acc1);
            DO_CHUNK(q4,  q5,  whi[2], wlo[2], acc0);
            DO_CHUNK(q6,  q7,  whi[3], wlo[3], acc1);
            DO_CHUNK(q8,  q9,  whi[4], wlo[4], acc0);
            DO_CHUNK(q10, q11, whi[5], wlo[5], acc1);
            DO_CHUNK(q12, q13, whi[6], wlo[6], acc0);
            DO_CHUNK(q14, q15, whi[7], wlo[7], acc1);
#undef DO_CHUNK
        }
        f32x4 asum = acc0 + acc1;
        *(f32x4*)&part[t & 1][w][ln][0] = asum;
        __syncthreads();

        if (w == 0) {
            f32x4 p0 = *(const f32x4*)&part[t & 1][0][ln][0];
            f32x4 p1 = *(const f32x4*)&part[t & 1][1][ln][0];
            f32x4 p2 = *(const f32x4*)&part[t & 1][2][ln][0];
            f32x4 p3 = *(const f32x4*)&part[t & 1][3][ln][0];
            f32x4 csum = (p0 + p1) + (p2 + p3);
            if (ln < 32) {
                int colp = blk * 16 + (ln & 15);
                int bb = (ln >> 4) * 4;
                unsigned int* slot_w = hpk + (size_t)(t & (RING - 1)) * 8192;
                unsigned int* slot_s = hpk + (size_t)((t + RING - 3) & (RING - 1)) * 8192;
                uint32_t pk[4], hb[4];
#pragma unroll
                for (int r = 0; r < 4; ++r) {
                    float x = xp[r] + csum[r] + bhh;
                    float h = tanhf(x);
                    uint32_t hi = f2bf(h);
                    float hif = __builtin_bit_cast(float, hi << 16);
                    uint32_t lo = f2bf(h - hif);
                    pk[r] = (hi << 16) | lo;
                    hb[r] = hi;
                }
                // 1) publish h-ring via atomic exchange (coherent-point write,
                //    stays MALL-resident; consumers gate on these values)
#pragma unroll
                for (int r = 0; r < 4; ++r)
                    (void)__hip_atomic_exchange(slot_w + (bb + r) * 1024 + colp, pk[r],
                                                __ATOMIC_RELAXED, __HIP_MEMORY_SCOPE_AGENT);
                // 2) sentinel refill of slot t+13 (also atomic, stays resident)
#pragma unroll
                for (int r = 0; r < 4; ++r)
                    (void)__hip_atomic_exchange(slot_s + (bb + r) * 1024 + colp, SEN,
                                                __ATOMIC_RELAXED, __HIP_MEMORY_SCOPE_AGENT);
                // 3) hs archive (plain cached store; read by k_fc next kernel)
#pragma unroll
                for (int r = 0; r < 4; ++r)
                    hs[(size_t)(t * NB + bb + r) * HID + colp] = (unsigned short)hb[r];
            }
        }
    }
}

// ---------------- fc: C[m][n] = hs[m][:] . W_fc[n][:] + b_fc[n], bf16 MFMA ----------------
// grid dim3(16,250): bm fast -> the 16 consumers of each B-tile dispatch adjacently
__global__ void k_fc(const unsigned short* __restrict__ A,   // [2048][1024] bf16
                     const unsigned short* __restrict__ Bw,  // [32000][1024] bf16
                     const float* __restrict__ bias,
                     float* __restrict__ out) {              // [8][256][32000] f32
    __shared__ __align__(16) unsigned short As[128 * 32];
    __shared__ __align__(16) unsigned short Bs[128 * 32];
    const int tid = threadIdx.x;
    const int w = tid >> 6, ln = tid & 63;
    const int bm = blockIdx.x, bn = blockIdx.y;
    const int wm = (w >> 1) * 64, wn = (w & 1) * 64;
    const int srow = tid >> 2;
    const int scol = (tid & 3) * 8;
    const unsigned short* Ag = A  + (size_t)(bm * 128 + srow) * 1024 + scol;
    const unsigned short* Bg = Bw + (size_t)(bn * 128 + srow) * 1024 + scol;
    unsigned short* ldsA0 = As + w * 512;
    unsigned short* ldsA1 = As + 2048 + w * 512;
    unsigned short* ldsB0 = Bs + w * 512;
    unsigned short* ldsB1 = Bs + 2048 + w * 512;

    f32x4 acc[4][4] = {};
    const int fr = ln & 15;
    const int kq = (ln >> 4) * 8;

    for (int kk = 0; kk < 1024; kk += 32) {
        __syncthreads();
        __builtin_amdgcn_global_load_lds((const AS1 void*)(Ag + kk),             (AS3 void*)ldsA0, 16, 0, 0);
        __builtin_amdgcn_global_load_lds((const AS1 void*)(Ag + 64 * 1024 + kk), (AS3 void*)ldsA1, 16, 0, 0);
        __builtin_amdgcn_global_load_lds((const AS1 void*)(Bg + kk),             (AS3 void*)ldsB0, 16, 0, 0);
        __builtin_amdgcn_global_load_lds((const AS1 void*)(Bg + 64 * 1024 + kk), (AS3 void*)ldsB1, 16, 0, 0);
        __syncthreads();
        bf16x8 af[4], bf[4];
#pragma unroll
        for (int i = 0; i < 4; ++i)
            af[i] = *(const bf16x8*)&As[(wm + i * 16 + fr) * 32 + kq];
#pragma unroll
        for (int j = 0; j < 4; ++j)
            bf[j] = *(const bf16x8*)&Bs[(wn + j * 16 + fr) * 32 + kq];
#pragma unroll
        for (int i = 0; i < 4; ++i)
#pragma unroll
            for (int j = 0; j < 4; ++j)
                acc[i][j] = __builtin_amdgcn_mfma_f32_16x16x32_bf16(af[i], bf[j], acc[i][j], 0, 0, 0);
    }

    const int fq = ln >> 4;
#pragma unroll
    for (int i = 0; i < 4; ++i) {
#pragma unroll
        for (int j = 0; j < 4; ++j) {
            int n = bn * 128 + wn + j * 16 + fr;
            float bv = bias[n];
#pragma unroll
            for (int r = 0; r < 4; ++r) {
                int m = bm * 128 + wm + i * 16 + fq * 4 + r;
                int t = m >> 3, b = m & 7;
                out[(size_t)b * T_SEQ * NOUT + (size_t)t * NOUT + n] = acc[i][j][r] + bv;
            }
        }
    }
}

extern "C" void kernel_launch(void* const* d_in, const int* in_sizes, int n_in,
                              void* d_out, int out_size, void* d_ws, size_t ws_size,
                              hipStream_t stream) {
    const int*   inputs = (const int*)d_in[0];
    const float* embed  = (const float*)d_in[1];
    const float* W_ih   = (const float*)d_in[2];
    const float* W_hh   = (const float*)d_in[3];
    const float* b_ih   = (const float*)d_in[4];
    const float* b_hh   = (const float*)d_in[5];
    const float* W_fc   = (const float*)d_in[6];
    const float* b_fc   = (const float*)d_in[7];
    float* out = (float*)d_out;

    char* ws = (char*)d_ws;
    unsigned int*   hpk   = (unsigned int*)(ws);                        // RING*8*1024*4 = 512 KB
    float*          xproj = (float*)(ws + 524288);                      // 8 MB
    unsigned short* hs    = (unsigned short*)(ws + 524288 + 8388608);   // 4 MB
    unsigned short* wfcb  = (unsigned short*)(ws + 524288 + 8388608 + 4194304); // 64 MB

    k_fill<<<128, 256, 0, stream>>>(hpk);
    k_convert_wfc<<<2048, 256, 0, stream>>>(W_fc, wfcb);
    k_xproj<<<dim3(16, 32), 256, 0, stream>>>(inputs, embed, W_ih, b_ih, xproj);
    k_rnn<<<RBLK, 256, 0, stream>>>(W_hh, b_hh, xproj, hpk, hs);
    k_fc<<<dim3(16, 250), 256, 0, stream>>>(hs, wfcb, b_fc, out);
}